// Round 3
// baseline (11852.789 us; speedup 1.0000x reference)
//
#include <hip/hip_runtime.h>

#define B_ 64
#define S_ 512
#define D_ 512
#define H_ 1024

typedef __attribute__((ext_vector_type(8))) short bf16x8;
typedef __attribute__((ext_vector_type(4))) float f32x4;
typedef unsigned short u16;
typedef unsigned int u32;

#define MFMA(a, b, c) __builtin_amdgcn_mfma_f32_16x16x32_bf16(a, b, c, 0, 0, 0)

__device__ __forceinline__ u16 f2bf(float f) {
    u32 u = __float_as_uint(f);
    u += 0x7fffu + ((u >> 16) & 1u);
    return (u16)(u >> 16);
}
__device__ __forceinline__ float sigm(float x) { return 1.0f / (1.0f + __expf(-x)); }
__device__ __forceinline__ float tanh_f(float x) { return 1.0f - 2.0f / (__expf(2.0f * x) + 1.0f); }

__device__ __forceinline__ bf16x8 cvt8(const float* p) {
    float4 f0 = ((const float4*)p)[0];
    float4 f1 = ((const float4*)p)[1];
    bf16x8 v;
    v[0] = (short)f2bf(f0.x); v[1] = (short)f2bf(f0.y);
    v[2] = (short)f2bf(f0.z); v[3] = (short)f2bf(f0.w);
    v[4] = (short)f2bf(f1.x); v[5] = (short)f2bf(f1.y);
    v[6] = (short)f2bf(f1.z); v[7] = (short)f2bf(f1.w);
    return v;
}

// ---- LLC-direct (MALL) access: sc0 sc1 = system scope, bypass L1+L2 (PROVEN path) ----
__device__ __forceinline__ void llc_ld(bf16x8& d, const u16* p) {
    asm volatile("global_load_dwordx4 %0, %1, off sc0 sc1" : "=v"(d) : "v"(p));
}
__device__ __forceinline__ void vm0() {
    asm volatile("s_waitcnt vmcnt(0)" ::: "memory");
}
__device__ __forceinline__ void fence_frag(bf16x8& d) {
    asm volatile("" : "+v"(d));
}
__device__ __forceinline__ void llc_st16(u16* p, u16 v) {
    u32 vv = v;
    asm volatile("global_store_short %0, %1, off sc0 sc1" :: "v"(p), "v"(vv) : "memory");
}
__device__ __forceinline__ void llc_st32(int* p, int v) {
    asm volatile("global_store_dword %0, %1, off sc0 sc1" :: "v"(p), "v"(v) : "memory");
}
__device__ __forceinline__ int llc_poll1(const int* p) {
    int v;
    asm volatile("global_load_dword %0, %1, off sc0 sc1\ns_waitcnt vmcnt(0)"
                 : "=v"(v) : "v"(p) : "memory");
    return v;
}
__device__ __forceinline__ void llc_ld_i4(int& v0, int& v1, int& v2, int& v3,
                                          const int* p0, const int* p1,
                                          const int* p2, const int* p3) {
    asm volatile("global_load_dword %0, %4, off sc0 sc1\n"
                 "global_load_dword %1, %5, off sc0 sc1\n"
                 "global_load_dword %2, %6, off sc0 sc1\n"
                 "global_load_dword %3, %7, off sc0 sc1\n"
                 "s_waitcnt vmcnt(0)"
                 : "=&v"(v0), "=&v"(v1), "=&v"(v2), "=&v"(v3)
                 : "v"(p0), "v"(p1), "v"(p2), "v"(p3) : "memory");
}

// ---------------- prep: fp32 weights -> bf16 concatenated [Wih | Whh], K-contiguous ----
__global__ void prep_w(const float* __restrict__ Wih, const float* __restrict__ Whh,
                       u16* __restrict__ Wc, int Kx, int Kw, int total8) {
    int idx = blockIdx.x * 256 + threadIdx.x;
    if (idx >= total8) return;
    int kc8 = Kw >> 3;
    int n = idx / kc8;
    int kc = (idx - n * kc8) << 3;
    const float* src = (kc < Kx) ? (Wih + (size_t)n * Kx + kc)
                                 : (Whh + (size_t)n * (Kw - Kx) + (kc - Kx));
    *(bf16x8*)(Wc + (size_t)n * Kw + kc) = cvt8(src);
}

// ---------------- prep: biases + h-state init + flag zero ----------------
__global__ void prep_misc2(const float* __restrict__ h0in,
                           const float* __restrict__ bih0, const float* __restrict__ bhh0,
                           const float* __restrict__ bih1, const float* __restrict__ bhh1,
                           float* __restrict__ bias0, float* __restrict__ bias1,
                           u16* __restrict__ h0a, u16* __restrict__ h0b,
                           u16* __restrict__ h1a, u16* __restrict__ h1b,
                           int* __restrict__ bar) {
    int idx = blockIdx.x * 256 + threadIdx.x;
    if (idx < 10240) bar[idx] = 0;   // pflag + regcnt + gbar + xdone + lflag region
    if (idx < 4096) { bias0[idx] = bih0[idx] + bhh0[idx]; return; }
    if (idx < 8192) { int i = idx - 4096; bias1[i] = bih1[i] + bhh1[i]; return; }
    int r = idx - 8192;
    if (r >= 2 * B_ * H_) return;
    int l = r >> 16;
    int rr = r & 65535;
    u16 hb = f2bf(h0in[r]);
    if (l == 0) { h0a[rr] = hb; h0b[rr] = hb; }
    else        { h1a[rr] = hb; h1b[rr] = hb; }
}

// ---------------- persistent LSTM kernel with per-XCD L2 mirrors -----------------------
// 256 blocks x 512 threads. Block bk: col-group cgp=bk>>1, row-half mh=bk&1.
// Producers publish h to MALL (sc0 sc1). Per XCD, 8 importer blocks pull each byte ONCE
// from MALL (consumer-fragment order) and write an XCD-private mirror with PLAIN
// write-through stores (-> own L2). Consumers use PLAIN loads for mirror data (same-XCD
// L2 hit). ALL flags go through MALL with sc0 sc1 on both sides (proven r0/r1 path) --
// no reliance on sc0-alone semantics anywhere. Mirror rotation is 4-deep so a consumer
// L1 line can never survive to its next use (~900KB streams through 32KB L1 between
// reuses). WAR: mirror[(p+1)&3] written only after ALL blocks completed iter p (pflag),
// so iter p-3 readers are done; h buffers 2-deep gated by per-XCD xdone (iter slack).
// All spins bounded -> no hang possible.
__global__ __launch_bounds__(512, 2) void lstm_persist(
    const float* __restrict__ x,
    const u16* __restrict__ W0c, const u16* __restrict__ W1c,
    const float* __restrict__ bias0, const float* __restrict__ bias1,
    const float* __restrict__ c0in,
    u16* __restrict__ h0a, u16* __restrict__ h0b,
    u16* __restrict__ h1a, u16* __restrict__ h1b,
    float* __restrict__ h1f,
    int* __restrict__ bar,
    u16* __restrict__ mirrA, u16* __restrict__ mirrB) {
    const int bk = blockIdx.x;
    const int cgp = bk >> 1;
    const int mh = bk & 1;
    const int tid = threadIdx.x;
    const int w = tid >> 6;
    const int lane = tid & 63;
    const int quad = lane >> 4;
    const int l16 = lane & 15;

    // flag regions inside bar (ints): [0..8191] pflag (bk*32); [8192..8207] regcnt;
    // [8208] gbar; [8216..8223] xdone; [8448 + xcc*64 ..] lflag (one line per XCD)
    int* pflag  = bar;
    int* regcnt = bar + 8192;
    int* gbar   = bar + 8208;
    int* xdone  = bar + 8216;

    // ---- startup: XCD discovery + registration + one-time grid barrier ----
    __shared__ int sh4[4];
    if (tid == 0) {
        int xc;
        asm volatile("s_getreg_b32 %0, hwreg(HW_REG_XCC_ID, 0, 4)" : "=s"(xc));
        xc &= 7;
        int rk = __hip_atomic_fetch_add(&regcnt[xc], 1, __ATOMIC_RELAXED, __HIP_MEMORY_SCOPE_AGENT);
        __hip_atomic_fetch_add(gbar, 1, __ATOMIC_RELAXED, __HIP_MEMORY_SCOPE_AGENT);
        for (int it = 0; it < 4000000; ++it) {
            if (__hip_atomic_load(gbar, __ATOMIC_RELAXED, __HIP_MEMORY_SCOPE_AGENT) >= 256) break;
            __builtin_amdgcn_s_sleep(2);
        }
        int msk = 0;
        for (int xx = 0; xx < 8; ++xx)
            if (__hip_atomic_load(&regcnt[xx], __ATOMIC_RELAXED, __HIP_MEMORY_SCOPE_AGENT) > 0)
                msk |= 1 << xx;
        int nx = __hip_atomic_load(&regcnt[xc], __ATOMIC_RELAXED, __HIP_MEMORY_SCOPE_AGENT);
        int im = (nx >= 8) ? 8 : (nx >= 4) ? 4 : (nx >= 2) ? 2 : 1;
        sh4[0] = xc; sh4[1] = rk; sh4[2] = im; sh4[3] = msk;
    }
    __syncthreads();
    const int xcc = sh4[0], rank = sh4[1], imp = sh4[2], xmask = sh4[3];
    const bool isImp = rank < imp;
    int* lflagX = bar + 8448 + xcc * 64;

    int gc[2];
    #pragma unroll
    for (int n = 0; n < 2; ++n) {
        int c = n * 16 + l16;
        gc[n] = (c >> 3) * 1024 + cgp * 8 + (c & 7);
    }

    // --- persistent weight fragments (loaded once, live in registers) ---
    bf16x8 w0x[2][2], w0h[2][4];
    bf16x8 w1f[2][8];
    #pragma unroll
    for (int n = 0; n < 2; ++n) {
        #pragma unroll
        for (int kf = 0; kf < 2; ++kf)
            w0x[n][kf] = *(const bf16x8*)(W0c + (size_t)gc[n] * 1536 + w * 64 + kf * 32 + quad * 8);
        #pragma unroll
        for (int kf = 0; kf < 4; ++kf)
            w0h[n][kf] = *(const bf16x8*)(W0c + (size_t)gc[n] * 1536 + 512 + w * 128 + kf * 32 + quad * 8);
        #pragma unroll
        for (int kf = 0; kf < 8; ++kf)
            w1f[n][kf] = *(const bf16x8*)(W1c + (size_t)gc[n] * 2048 + w * 256 + kf * 32 + quad * 8);
    }

    __shared__ __align__(16) float partA[8 * 32 * 36];
    __shared__ __align__(16) float partB[8 * 32 * 36];
    __shared__ float c0l[256], c1l[256];
    __shared__ __align__(16) float b0l[32], b1l[32];

    if (tid < 32) {
        int gg = tid >> 3, j = tid & 7;
        b0l[j * 4 + gg] = bias0[gg * 1024 + cgp * 8 + j];
        b1l[j * 4 + gg] = bias1[gg * 1024 + cgp * 8 + j];
    }
    if (tid < 256) {
        int b = tid >> 3, j = tid & 7;
        int gi = (mh * 32 + b) * 1024 + cgp * 8 + j;
        c0l[tid] = c0in[gi];
        c1l[tid] = c0in[65536 + gi];
    }
    __syncthreads();

    const int brow0 = mh * 32 + l16;
    const int brow1 = brow0 + 16;
    const int co0 = (l16 & 7) * 4 + (l16 >> 3);
    const int co1 = co0 + 2;

    f32x4 xacc[2][2];
    #define XPART(t)                                                                 \
        {                                                                            \
            xacc[0][0] = (f32x4){0.f,0.f,0.f,0.f}; xacc[0][1] = (f32x4){0.f,0.f,0.f,0.f}; \
            xacc[1][0] = (f32x4){0.f,0.f,0.f,0.f}; xacc[1][1] = (f32x4){0.f,0.f,0.f,0.f}; \
            _Pragma("unroll")                                                        \
            for (int kf = 0; kf < 2; ++kf) {                                         \
                int k = w * 64 + kf * 32 + quad * 8;                                 \
                bf16x8 a0_ = cvt8(x + (size_t)brow0 * 262144 + (t) * 512 + k);       \
                bf16x8 a1_ = cvt8(x + (size_t)brow1 * 262144 + (t) * 512 + k);       \
                xacc[0][0] = MFMA(a0_, w0x[0][kf], xacc[0][0]);                      \
                xacc[0][1] = MFMA(a0_, w0x[1][kf], xacc[0][1]);                      \
                xacc[1][0] = MFMA(a1_, w0x[0][kf], xacc[1][0]);                      \
                xacc[1][1] = MFMA(a1_, w0x[1][kf], xacc[1][1]);                      \
            }                                                                        \
        }

    XPART(0);

    for (int p = 0; p <= S_; ++p) {
        const int rd = p & 1;           // h double-buffer selector
        const int rot = p & 3;          // mirror 4-deep rotation selector
        u16* h0w_ = rd ? h0a : h0b;
        u16* h1w_ = rd ? h1a : h1b;

        // ---- WAR gate: all active XCDs imported iter p-1 (one-iter slack) ----
        if (p >= 2) {
            const int* xp = xdone + (lane & 7);
            const bool act = (xmask >> (lane & 7)) & 1;
            for (int it = 0; it < 200000; ++it) {
                int v = llc_poll1(xp);
                if (__all(!act || v >= p - 1)) break;
            }
        }
        // ---- consumer wait: own-XCD mirror ready for iter p (flags via MALL) ----
        if (p >= 1) {
            const int* fp = lflagX + (((lane & 7) < imp) ? (lane & 7) : 0);
            for (int it = 0; it < 400000; ++it) {
                int v = llc_poll1(fp);
                if (__all(v >= p)) break;
            }
        }

        // ---- operand loads: PLAIN loads from own-XCD mirror (L2 hit) ----
        bf16x8 a0[4], a1[4], pb0[8], pb1[8];
        if (p < S_) {
            if (p == 0) {
                #pragma unroll
                for (int kf = 0; kf < 4; ++kf) {
                    int ko = w * 128 + kf * 32 + quad * 8;
                    llc_ld(a0[kf], h0a + brow0 * 1024 + ko);
                    llc_ld(a1[kf], h0a + brow1 * 1024 + ko);
                }
                vm0();
                #pragma unroll
                for (int kf = 0; kf < 4; ++kf) { fence_frag(a0[kf]); fence_frag(a1[kf]); }
            } else {
                const u16* MAc = mirrA + (((size_t)xcc * 4 + rot) * 2 + mh) * 32768 + (size_t)tid * 64;
                #pragma unroll
                for (int kf = 0; kf < 4; ++kf) {
                    a0[kf] = *(const bf16x8*)(MAc + kf * 16);
                    a1[kf] = *(const bf16x8*)(MAc + kf * 16 + 8);
                }
            }
        }
        if (p >= 1) {
            const u16* MBc = mirrB + (((size_t)xcc * 4 + rot) * 2 + mh) * 65536 + (size_t)tid * 128;
            #pragma unroll
            for (int kf = 0; kf < 8; ++kf) {
                pb0[kf] = *(const bf16x8*)(MBc + kf * 16);
                pb1[kf] = *(const bf16x8*)(MBc + kf * 16 + 8);
            }
        }

        // ---------- stage A: layer 0, step p (h-part; x-part precomputed) ----------
        if (p < S_) {
            f32x4 acc00 = xacc[0][0], acc01 = xacc[0][1];
            f32x4 acc10 = xacc[1][0], acc11 = xacc[1][1];
            #pragma unroll
            for (int kf = 0; kf < 4; ++kf) {
                acc00 = MFMA(a0[kf], w0h[0][kf], acc00);
                acc01 = MFMA(a0[kf], w0h[1][kf], acc01);
                acc10 = MFMA(a1[kf], w0h[0][kf], acc10);
                acc11 = MFMA(a1[kf], w0h[1][kf], acc11);
            }
            #pragma unroll
            for (int r = 0; r < 4; ++r) {
                int b0 = quad * 4 + r, b1 = b0 + 16;
                partA[w * 1152 + b0 * 36 + co0] = acc00[r];
                partA[w * 1152 + b0 * 36 + co1] = acc01[r];
                partA[w * 1152 + b1 * 36 + co0] = acc10[r];
                partA[w * 1152 + b1 * 36 + co1] = acc11[r];
            }
        }
        __syncthreads();

        // ---- layer-0 reduce overlaps layer-1 MFMA ----
        if (p < S_ && tid < 256) {
            int b = tid >> 3, j = tid & 7;
            f32x4 s = *(const f32x4*)&b0l[j * 4];
            #pragma unroll
            for (int w8 = 0; w8 < 8; ++w8)
                s += *(const f32x4*)&partA[w8 * 1152 + b * 36 + j * 4];
            float c = c0l[tid];
            float cn = sigm(s[1]) * c + sigm(s[0]) * tanh_f(s[2]);
            float hn = sigm(s[3]) * tanh_f(cn);
            c0l[tid] = cn;
            llc_st16(h0w_ + (mh * 32 + b) * 1024 + cgp * 8 + j, f2bf(hn));
        }

        // ---------- stage B: layer 1, step p-1 ----------
        if (p >= 1) {
            f32x4 acc00 = {0.f,0.f,0.f,0.f}, acc01 = {0.f,0.f,0.f,0.f};
            f32x4 acc10 = {0.f,0.f,0.f,0.f}, acc11 = {0.f,0.f,0.f,0.f};
            #pragma unroll
            for (int kf = 0; kf < 8; ++kf) {
                acc00 = MFMA(pb0[kf], w1f[0][kf], acc00);
                acc01 = MFMA(pb0[kf], w1f[1][kf], acc01);
                acc10 = MFMA(pb1[kf], w1f[0][kf], acc10);
                acc11 = MFMA(pb1[kf], w1f[1][kf], acc11);
            }
            #pragma unroll
            for (int r = 0; r < 4; ++r) {
                int b0 = quad * 4 + r, b1 = b0 + 16;
                partB[w * 1152 + b0 * 36 + co0] = acc00[r];
                partB[w * 1152 + b0 * 36 + co1] = acc01[r];
                partB[w * 1152 + b1 * 36 + co0] = acc10[r];
                partB[w * 1152 + b1 * 36 + co1] = acc11[r];
            }
        }
        __syncthreads();
        if (p >= 1 && tid < 256) {
            int b = tid >> 3, j = tid & 7;
            f32x4 s = *(const f32x4*)&b1l[j * 4];
            #pragma unroll
            for (int w8 = 0; w8 < 8; ++w8)
                s += *(const f32x4*)&partB[w8 * 1152 + b * 36 + j * 4];
            float c = c1l[tid];
            float cn = sigm(s[1]) * c + sigm(s[0]) * tanh_f(s[2]);
            float hn = sigm(s[3]) * tanh_f(cn);
            c1l[tid] = cn;
            int gi = (mh * 32 + b) * 1024 + cgp * 8 + j;
            llc_st16(h1w_ + gi, f2bf(hn));
            if (p == S_) h1f[gi] = hn;
        }

        // ---- tail: post pflag, importers build next mirror, prefetch next x-part ----
        if (p < S_) {
            vm0();
            __syncthreads();
            if (tid == 0) llc_st32(pflag + bk * 32, p + 1);

            if (isImp) {
                // wave 0 waits for all 256 producer flags >= p+1 (MALL polls)
                if (w == 0) {
                    const int* f0 = pflag + (lane * 4 + 0) * 32;
                    const int* f1 = pflag + (lane * 4 + 1) * 32;
                    const int* f2 = pflag + (lane * 4 + 2) * 32;
                    const int* f3 = pflag + (lane * 4 + 3) * 32;
                    for (int it = 0; it < 200000; ++it) {
                        int v0, v1, v2, v3;
                        llc_ld_i4(v0, v1, v2, v3, f0, f1, f2, f3);
                        int mn = v0 < v1 ? v0 : v1;
                        int mn2 = v2 < v3 ? v2 : v3;
                        mn = mn < mn2 ? mn : mn2;
                        if (__all(mn >= p + 1)) break;
                    }
                }
                __syncthreads();
                const int rd2 = (p + 1) & 1;
                const int rot2 = (p + 1) & 3;
                const u16* H0 = rd2 ? h0b : h0a;
                const u16* H1 = rd2 ? h1b : h1a;
                u16* MAw = mirrA + ((size_t)xcc * 4 + rot2) * 2 * 32768;
                u16* MBw = mirrB + ((size_t)xcc * 4 + rot2) * 2 * 65536;

                if (imp == 8) {
                    // 4096 threads, 6 chunks each (wave-uniform decode)
                    const int sub = rank & 1;
                    const int s12 = (rank >> 1) * 512 + tid;
                    const int hf = s12 >> 10;
                    const int pr = s12 & 1023;
                    const int mh2 = pr >> 9, tc = pr & 511;
                    const int wc = tc >> 6, qc = (tc >> 4) & 3, lc = tc & 15;
                    const size_t r0 = (size_t)(mh2 * 32 + lc) * 1024 + qc * 8;
                    const size_t r1 = r0 + 16384;
                    u16* dA = MAw + mh2 * 32768 + tc * 64;
                    u16* dB = MBw + mh2 * 65536 + tc * 128;
                    bf16x8 t0, t1, t2, t3, t4, t5;
                    if (hf == 0) {
                        if (sub == 0) {
                            llc_ld(t0, H0 + r0 + wc * 128 + 0);
                            llc_ld(t1, H0 + r1 + wc * 128 + 0);
                            llc_ld(t2, H0 + r0 + wc * 128 + 32);
                            llc_ld(t3, H0 + r1 + wc * 128 + 32);
                            llc_ld(t4, H0 + r0 + wc * 128 + 64);
                            llc_ld(t5, H0 + r1 + wc * 128 + 64);
                            vm0();
                            fence_frag(t0); fence_frag(t1); fence_frag(t2);
                            fence_frag(t3); fence_frag(t4); fence_frag(t5);
                            *(bf16x8*)(dA + 0)  = t0; *(bf16x8*)(dA + 8)  = t1;
                            *(bf16x8*)(dA + 16) = t2; *(bf16x8*)(dA + 24) = t3;
                            *(bf16x8*)(dA + 32) = t4; *(bf16x8*)(dA + 40) = t5;
                        } else {
                            llc_ld(t0, H0 + r0 + wc * 128 + 96);
                            llc_ld(t1, H0 + r1 + wc * 128 + 96);
                            { int k = wc * 256;      const u16* Sp = (k < 1024) ? H0 : H1;
                              llc_ld(t2, Sp + r0 + (k & 1023)); llc_ld(t3, Sp + r1 + (k & 1023)); }
                            { int k = wc * 256 + 32; const u16* Sp = (k < 1024) ? H0 : H1;
                              llc_ld(t4, Sp + r0 + (k & 1023)); llc_ld(t5, Sp + r1 + (k & 1023)); }
                            vm0();
                            fence_frag(t0); fence_frag(t1); fence_frag(t2);
                            fence_frag(t3); fence_frag(t4); fence_frag(t5);
                            *(bf16x8*)(dA + 48) = t0; *(bf16x8*)(dA + 56) = t1;
                            *(bf16x8*)(dB + 0)  = t2; *(bf16x8*)(dB + 8)  = t3;
                            *(bf16x8*)(dB + 16) = t4; *(bf16x8*)(dB + 24) = t5;
                        }
                    } else {
                        const int kfb = 2 + sub * 3;
                        { int k = wc * 256 + (kfb + 0) * 32; const u16* Sp = (k < 1024) ? H0 : H1;
                          llc_ld(t0, Sp + r0 + (k & 1023)); llc_ld(t1, Sp + r1 + (k & 1023)); }
                        { int k = wc * 256 + (kfb + 1) * 32; const u16* Sp = (k < 1024) ? H0 : H1;
                          llc_ld(t2, Sp + r0 + (k & 1023)); llc_ld(t3, Sp + r1 + (k & 1023)); }
                        { int k = wc * 256 + (kfb + 2) * 32; const u16* Sp = (k < 1024) ? H0 : H1;
                          llc_ld(t4, Sp + r0 + (k & 1023)); llc_ld(t5, Sp + r1 + (k & 1023)); }
                        vm0();
                        fence_frag(t0); fence_frag(t1); fence_frag(t2);
                        fence_frag(t3); fence_frag(t4); fence_frag(t5);
                        *(bf16x8*)(dB + (kfb + 0) * 16)     = t0;
                        *(bf16x8*)(dB + (kfb + 0) * 16 + 8) = t1;
                        *(bf16x8*)(dB + (kfb + 1) * 16)     = t2;
                        *(bf16x8*)(dB + (kfb + 1) * 16 + 8) = t3;
                        *(bf16x8*)(dB + (kfb + 2) * 16)     = t4;
                        *(bf16x8*)(dB + (kfb + 2) * 16 + 8) = t5;
                    }
                } else {
                    // generic fallback (imp in {1,2,4}): 12-chunk slots, stride imp*512
                    for (int s = rank * 512 + tid; s < 2048; s += imp * 512) {
                        const int hf = s >> 10;
                        const int pr = s & 1023;
                        const int mh2 = pr >> 9, tc = pr & 511;
                        const int wc = tc >> 6, qc = (tc >> 4) & 3, lc = tc & 15;
                        const size_t r0 = (size_t)(mh2 * 32 + lc) * 1024 + qc * 8;
                        const size_t r1 = r0 + 16384;
                        u16* dA = MAw + mh2 * 32768 + tc * 64;
                        u16* dB = MBw + mh2 * 65536 + tc * 128;
                        bf16x8 t0, t1, t2, t3, t4, t5;
                        #pragma unroll
                        for (int g = 0; g < 2; ++g) {
                            if (hf == 0) {
                                if (g == 0) {
                                    llc_ld(t0, H0 + r0 + wc * 128 + 0);
                                    llc_ld(t1, H0 + r1 + wc * 128 + 0);
                                    llc_ld(t2, H0 + r0 + wc * 128 + 32);
                                    llc_ld(t3, H0 + r1 + wc * 128 + 32);
                                    llc_ld(t4, H0 + r0 + wc * 128 + 64);
                                    llc_ld(t5, H0 + r1 + wc * 128 + 64);
                                } else {
                                    llc_ld(t0, H0 + r0 + wc * 128 + 96);
                                    llc_ld(t1, H0 + r1 + wc * 128 + 96);
                                    { int k = wc * 256;      const u16* Sp = (k < 1024) ? H0 : H1;
                                      llc_ld(t2, Sp + r0 + (k & 1023)); llc_ld(t3, Sp + r1 + (k & 1023)); }
                                    { int k = wc * 256 + 32; const u16* Sp = (k < 1024) ? H0 : H1;
                                      llc_ld(t4, Sp + r0 + (k & 1023)); llc_ld(t5, Sp + r1 + (k & 1023)); }
                                }
                            } else {
                                const int kfb = 2 + g * 3;
                                { int k = wc * 256 + (kfb + 0) * 32; const u16* Sp = (k < 1024) ? H0 : H1;
                                  llc_ld(t0, Sp + r0 + (k & 1023)); llc_ld(t1, Sp + r1 + (k & 1023)); }
                                { int k = wc * 256 + (kfb + 1) * 32; const u16* Sp = (k < 1024) ? H0 : H1;
                                  llc_ld(t2, Sp + r0 + (k & 1023)); llc_ld(t3, Sp + r1 + (k & 1023)); }
                                { int k = wc * 256 + (kfb + 2) * 32; const u16* Sp = (k < 1024) ? H0 : H1;
                                  llc_ld(t4, Sp + r0 + (k & 1023)); llc_ld(t5, Sp + r1 + (k & 1023)); }
                            }
                            vm0();
                            fence_frag(t0); fence_frag(t1); fence_frag(t2);
                            fence_frag(t3); fence_frag(t4); fence_frag(t5);
                            if (hf == 0) {
                                if (g == 0) {
                                    *(bf16x8*)(dA + 0)  = t0; *(bf16x8*)(dA + 8)  = t1;
                                    *(bf16x8*)(dA + 16) = t2; *(bf16x8*)(dA + 24) = t3;
                                    *(bf16x8*)(dA + 32) = t4; *(bf16x8*)(dA + 40) = t5;
                                } else {
                                    *(bf16x8*)(dA + 48) = t0; *(bf16x8*)(dA + 56) = t1;
                                    *(bf16x8*)(dB + 0)  = t2; *(bf16x8*)(dB + 8)  = t3;
                                    *(bf16x8*)(dB + 16) = t4; *(bf16x8*)(dB + 24) = t5;
                                }
                            } else {
                                const int kfb = 2 + g * 3;
                                *(bf16x8*)(dB + (kfb + 0) * 16)     = t0;
                                *(bf16x8*)(dB + (kfb + 0) * 16 + 8) = t1;
                                *(bf16x8*)(dB + (kfb + 1) * 16)     = t2;
                                *(bf16x8*)(dB + (kfb + 1) * 16 + 8) = t3;
                                *(bf16x8*)(dB + (kfb + 2) * 16)     = t4;
                                *(bf16x8*)(dB + (kfb + 2) * 16 + 8) = t5;
                            }
                        }
                    }
                }
                vm0();              // mirror plain stores drained to own L2
                __syncthreads();
                if (tid == 0)
                    llc_st32(lflagX + rank, p + 1);   // flag via MALL (proven path)
                if (rank == 0 && w == 0) {
                    // aggregate: all importers done -> post xdone (MALL) for WAR gating
                    const int* sf = lflagX + (lane & 7);
                    for (int it = 0; it < 300000; ++it) {
                        int v = llc_poll1(sf);
                        if (__all(v >= p + 1 || (lane & 7) >= imp)) break;
                    }
                    if (lane == 0) llc_st32(xdone + xcc, p + 1);
                }
            }
            if (p + 1 < S_) XPART(p + 1);
        }
    }
}

// ---------------- final FC: out[b,o] = h1 . Wfc[o] + bfc[o] ----------------
__global__ void fc_k(const float* __restrict__ h1f, const float* __restrict__ Wfc,
                     const float* __restrict__ bfc, float* __restrict__ out) {
    int idx = blockIdx.x * 256 + threadIdx.x;
    if (idx >= 64 * 1000) return;
    int o = idx % 1000;
    int b = idx / 1000;
    const float4* hr = (const float4*)(h1f + b * H_);
    const float4* wr = (const float4*)(Wfc + (size_t)o * H_);
    float s = 0.f;
    #pragma unroll 4
    for (int k = 0; k < 256; ++k) {
        float4 a = hr[k];
        float4 w = wr[k];
        s += a.x * w.x + a.y * w.y + a.z * w.z + a.w * w.w;
    }
    out[idx] = s + bfc[o];
}

extern "C" void kernel_launch(void* const* d_in, const int* in_sizes, int n_in,
                              void* d_out, int out_size, void* d_ws, size_t ws_size,
                              hipStream_t stream) {
    const float* x    = (const float*)d_in[0];
    const float* h0in = (const float*)d_in[1];
    const float* c0in = (const float*)d_in[2];
    const float* Wih0 = (const float*)d_in[3];
    const float* Whh0 = (const float*)d_in[4];
    const float* bih0 = (const float*)d_in[5];
    const float* bhh0 = (const float*)d_in[6];
    const float* Wih1 = (const float*)d_in[7];
    const float* Whh1 = (const float*)d_in[8];
    const float* bih1 = (const float*)d_in[9];
    const float* bhh1 = (const float*)d_in[10];
    const float* Wfc  = (const float*)d_in[11];
    const float* bfc  = (const float*)d_in[12];
    float* out = (float*)d_out;

    char* ws = (char*)d_ws;
    size_t off = 0;
    auto alloc = [&](size_t bytes) {
        void* p = ws + off;
        off += (bytes + 255) & ~(size_t)255;
        return p;
    };
    u16* W0c   = (u16*)alloc((size_t)4096 * 1536 * 2);
    u16* W1c   = (u16*)alloc((size_t)4096 * 2048 * 2);
    float* bias0 = (float*)alloc(4096 * 4);
    float* bias1 = (float*)alloc(4096 * 4);
    u16* h0A   = (u16*)alloc(B_ * H_ * 2);
    u16* h0B   = (u16*)alloc(B_ * H_ * 2);
    u16* h1A   = (u16*)alloc(B_ * H_ * 2);
    u16* h1B   = (u16*)alloc(B_ * H_ * 2);
    float* h1f = (float*)alloc(B_ * H_ * 4);
    int* bar   = (int*)alloc(40960);                           // flags (zeroed in prep)
    u16* mirrA = (u16*)alloc((size_t)8 * 4 * 2 * 32768 * 2);   // 4 MB: a-frag mirrors (4-rot)
    u16* mirrB = (u16*)alloc((size_t)8 * 4 * 2 * 65536 * 2);   // 8 MB: pb-frag mirrors (4-rot)

    prep_w<<<786432 / 256, 256, 0, stream>>>(Wih0, Whh0, W0c, 512, 1536, 786432);
    prep_w<<<1048576 / 256, 256, 0, stream>>>(Wih1, Whh1, W1c, 1024, 2048, 1048576);
    prep_misc2<<<(8192 + 2 * B_ * H_ + 255) / 256, 256, 0, stream>>>(
        h0in, bih0, bhh0, bih1, bhh1, bias0, bias1, h0A, h0B, h1A, h1B, bar);

    void* args[] = {(void*)&x, (void*)&W0c, (void*)&W1c, (void*)&bias0, (void*)&bias1,
                    (void*)&c0in, (void*)&h0A, (void*)&h0B, (void*)&h1A, (void*)&h1B,
                    (void*)&h1f, (void*)&bar, (void*)&mirrA, (void*)&mirrB};
    hipLaunchCooperativeKernel((void*)lstm_persist, dim3(256), dim3(512), args, 0, stream);

    fc_k<<<(64000 + 255) / 256, 256, 0, stream>>>(h1f, Wfc, bfc, out);
}

// Round 4
// 5408.473 us; speedup vs baseline: 2.1915x; 2.1915x over previous
//
#include <hip/hip_runtime.h>

#define B_ 64
#define S_ 512
#define D_ 512
#define H_ 1024

typedef __attribute__((ext_vector_type(8))) short bf16x8;
typedef __attribute__((ext_vector_type(4))) float f32x4;
typedef unsigned short u16;
typedef unsigned int u32;

#define MFMA(a, b, c) __builtin_amdgcn_mfma_f32_16x16x32_bf16(a, b, c, 0, 0, 0)

__device__ __forceinline__ u16 f2bf(float f) {
    u32 u = __float_as_uint(f);
    u += 0x7fffu + ((u >> 16) & 1u);
    return (u16)(u >> 16);
}
__device__ __forceinline__ float sigm(float x) { return 1.0f / (1.0f + __expf(-x)); }
__device__ __forceinline__ float tanh_f(float x) { return 1.0f - 2.0f / (__expf(2.0f * x) + 1.0f); }

__device__ __forceinline__ bf16x8 cvt8(const float* p) {
    float4 f0 = ((const float4*)p)[0];
    float4 f1 = ((const float4*)p)[1];
    bf16x8 v;
    v[0] = (short)f2bf(f0.x); v[1] = (short)f2bf(f0.y);
    v[2] = (short)f2bf(f0.z); v[3] = (short)f2bf(f0.w);
    v[4] = (short)f2bf(f1.x); v[5] = (short)f2bf(f1.y);
    v[6] = (short)f2bf(f1.z); v[7] = (short)f2bf(f1.w);
    return v;
}

// ---- LLC-direct access helpers: sc0 sc1 = bypass L1+L2, served by Infinity Cache ----
// (cross-XCD coherent WITHOUT any cache maintenance; the r0-proven exchange path)
__device__ __forceinline__ void llc_ld(bf16x8& d, const u16* p) {
    asm volatile("global_load_dwordx4 %0, %1, off sc0 sc1" : "=v"(d) : "v"(p));
}
__device__ __forceinline__ void vm0() {
    asm volatile("s_waitcnt vmcnt(0)" ::: "memory");
}
__device__ __forceinline__ void fence_frag(bf16x8& d) {
    asm volatile("" : "+v"(d));   // pin uses after the preceding vm0()
}
__device__ __forceinline__ void llc_st16(u16* p, u16 v) {
    u32 vv = v;
    asm volatile("global_store_short %0, %1, off sc0 sc1" :: "v"(p), "v"(vv) : "memory");
}

// ---------------- prep: fp32 weights -> bf16 concatenated [Wih | Whh], K-contiguous ----
__global__ void prep_w(const float* __restrict__ Wih, const float* __restrict__ Whh,
                       u16* __restrict__ Wc, int Kx, int Kw, int total8) {
    int idx = blockIdx.x * 256 + threadIdx.x;
    if (idx >= total8) return;
    int kc8 = Kw >> 3;
    int n = idx / kc8;
    int kc = (idx - n * kc8) << 3;
    const float* src = (kc < Kx) ? (Wih + (size_t)n * Kx + kc)
                                 : (Whh + (size_t)n * (Kw - Kx) + (kc - Kx));
    *(bf16x8*)(Wc + (size_t)n * Kw + kc) = cvt8(src);
}

// ---------------- prep: biases + h-state init (SWIZZLED) + barrier counter zero --------
// h exchange layout: h[k8][row][8] with k8 = col>>3  ->  idx = k8*512 + row*8 + (col&7).
// Producers write dense 128B/wave; consumer wave-loads are 4x 256B dense segments.
__global__ void prep_misc2(const float* __restrict__ h0in,
                           const float* __restrict__ bih0, const float* __restrict__ bhh0,
                           const float* __restrict__ bih1, const float* __restrict__ bhh1,
                           float* __restrict__ bias0, float* __restrict__ bias1,
                           u16* __restrict__ h0a, u16* __restrict__ h0b,
                           u16* __restrict__ h1a, u16* __restrict__ h1b,
                           int* __restrict__ bar) {
    int idx = blockIdx.x * 256 + threadIdx.x;
    if (idx < 1024) bar[idx] = 0;
    if (idx < 4096) { bias0[idx] = bih0[idx] + bhh0[idx]; return; }
    if (idx < 8192) { int i = idx - 4096; bias1[i] = bih1[i] + bhh1[i]; return; }
    int r = idx - 8192;
    if (r >= 2 * B_ * H_) return;
    int l = r >> 16;
    int rr = r & 65535;
    int b = rr >> 10, col = rr & 1023;
    int sidx = (col >> 3) * 512 + b * 8 + (col & 7);
    u16 hb = f2bf(h0in[r]);
    if (l == 0) { h0a[sidx] = hb; h0b[sidx] = hb; }
    else        { h1a[sidx] = hb; h1b[sidx] = hb; }
}

// ---------------- persistent LSTM kernel: weights live in registers across all steps ---
// 256 blocks (1/CU) x 512 threads (8 waves). Block bk: col-group cgp=bk>>1 (8 h-cols ->
// 32 gate cols per layer), row-half mh=bk&1 (32 batch rows).
// Cross-block h-state goes through LLC-direct (sc0 sc1) loads/stores in the SWIZZLED
// fragment layout h[k8][row][8] -> every exchange transaction is a fully-dense 64B
// granule (r0's row-major layout scattered 16B/lane over distinct lines = 4x MALL
// over-fetch, which was the measured 11.5us/step bandwidth wall).
// Flat grid barrier is r0's proven atomic counter. Spins bounded.
__global__ __launch_bounds__(512, 2) void lstm_persist(
    const float* __restrict__ x,
    const u16* __restrict__ W0c, const u16* __restrict__ W1c,
    const float* __restrict__ bias0, const float* __restrict__ bias1,
    const float* __restrict__ c0in,
    u16* __restrict__ h0a, u16* __restrict__ h0b,
    u16* __restrict__ h1a, u16* __restrict__ h1b,
    float* __restrict__ h1f,
    int* __restrict__ bar) {
    const int bk = blockIdx.x;
    const int cgp = bk >> 1;
    const int mh = bk & 1;
    const int tid = threadIdx.x;
    const int w = tid >> 6;
    const int lane = tid & 63;
    const int quad = lane >> 4;
    const int l16 = lane & 15;

    int gc[2];
    #pragma unroll
    for (int n = 0; n < 2; ++n) {
        int c = n * 16 + l16;
        gc[n] = (c >> 3) * 1024 + cgp * 8 + (c & 7);
    }

    // --- persistent weight fragments (loaded once, live in registers) ---
    bf16x8 w0x[2][2], w0h[2][4];
    bf16x8 w1f[2][8];
    #pragma unroll
    for (int n = 0; n < 2; ++n) {
        #pragma unroll
        for (int kf = 0; kf < 2; ++kf)
            w0x[n][kf] = *(const bf16x8*)(W0c + (size_t)gc[n] * 1536 + w * 64 + kf * 32 + quad * 8);
        #pragma unroll
        for (int kf = 0; kf < 4; ++kf)
            w0h[n][kf] = *(const bf16x8*)(W0c + (size_t)gc[n] * 1536 + 512 + w * 128 + kf * 32 + quad * 8);
        #pragma unroll
        for (int kf = 0; kf < 8; ++kf)
            w1f[n][kf] = *(const bf16x8*)(W1c + (size_t)gc[n] * 2048 + w * 256 + kf * 32 + quad * 8);
    }

    __shared__ float part[8 * 32 * 37];
    __shared__ float c0l[256], c1l[256];
    __shared__ float b0l[32], b1l[32];

    if (tid < 32) {
        int gg = tid >> 3, j = tid & 7;
        b0l[tid] = bias0[gg * 1024 + cgp * 8 + j];
        b1l[tid] = bias1[gg * 1024 + cgp * 8 + j];
    }
    if (tid < 256) {
        int b = tid >> 3, j = tid & 7;
        int gi = (mh * 32 + b) * 1024 + cgp * 8 + j;
        c0l[tid] = c0in[gi];
        c1l[tid] = c0in[65536 + gi];
    }
    __syncthreads();

    const int brow0 = mh * 32 + l16;
    const int brow1 = brow0 + 16;

    // x-part accumulators (plain cached loads -- L2 stays warm)
    f32x4 xacc[2][2];
    #define XPART(t)                                                                 \
        {                                                                            \
            xacc[0][0] = (f32x4){0.f,0.f,0.f,0.f}; xacc[0][1] = (f32x4){0.f,0.f,0.f,0.f}; \
            xacc[1][0] = (f32x4){0.f,0.f,0.f,0.f}; xacc[1][1] = (f32x4){0.f,0.f,0.f,0.f}; \
            _Pragma("unroll")                                                        \
            for (int kf = 0; kf < 2; ++kf) {                                         \
                int k = w * 64 + kf * 32 + quad * 8;                                 \
                bf16x8 a0_ = cvt8(x + (size_t)brow0 * 262144 + (t) * 512 + k);       \
                bf16x8 a1_ = cvt8(x + (size_t)brow1 * 262144 + (t) * 512 + k);       \
                xacc[0][0] = MFMA(a0_, w0x[0][kf], xacc[0][0]);                      \
                xacc[0][1] = MFMA(a0_, w0x[1][kf], xacc[0][1]);                      \
                xacc[1][0] = MFMA(a1_, w0x[0][kf], xacc[1][0]);                      \
                xacc[1][1] = MFMA(a1_, w0x[1][kf], xacc[1][1]);                      \
            }                                                                        \
        }

    XPART(0);

    for (int p = 0; p <= S_; ++p) {
        const int rd = p & 1;
        const u16* h0r = rd ? h0b : h0a;
        u16*       h0w_ = rd ? h0a : h0b;
        const u16* h1r = rd ? h1b : h1a;
        u16*       h1w_ = rd ? h1a : h1b;

        // ---- flat barrier wait (relaxed polls only; bounded -> no hang possible) ----
        if (p > 0) {
            if (tid == 0) {
                int target = 256 * p;
                for (int it = 0; it < 20000; ++it) {
                    if (__hip_atomic_load(&bar[0], __ATOMIC_RELAXED, __HIP_MEMORY_SCOPE_AGENT) >= target)
                        break;
                    __builtin_amdgcn_s_sleep(1);
                }
            }
            __syncthreads();
        }

        // ---- issue stage-A loads (swizzled, dense), wait, then issue stage-B loads ----
        bf16x8 a0[4], a1[4];
        if (p < S_) {
            #pragma unroll
            for (int kf = 0; kf < 4; ++kf) {
                int k8 = w * 16 + kf * 4 + quad;
                llc_ld(a0[kf], h0r + (k8 * 64 + brow0) * 8);
                llc_ld(a1[kf], h0r + (k8 * 64 + brow1) * 8);
            }
            vm0();
            #pragma unroll
            for (int kf = 0; kf < 4; ++kf) { fence_frag(a0[kf]); fence_frag(a1[kf]); }
        }
        bf16x8 pb0[8], pb1[8];
        if (p >= 1) {
            #pragma unroll
            for (int kf = 0; kf < 8; ++kf) {
                int k = w * 256 + kf * 32;
                const u16* src = (k < 1024) ? h0r : h1r;
                int k8 = ((k & 1023) >> 3) + quad;
                llc_ld(pb0[kf], src + (k8 * 64 + brow0) * 8);
                llc_ld(pb1[kf], src + (k8 * 64 + brow1) * 8);
            }
        }

        // ---------- stage A: layer 0, step p (h-part; x-part precomputed) ----------
        if (p < S_) {
            f32x4 acc00 = xacc[0][0], acc01 = xacc[0][1];
            f32x4 acc10 = xacc[1][0], acc11 = xacc[1][1];
            #pragma unroll
            for (int kf = 0; kf < 4; ++kf) {
                acc00 = MFMA(a0[kf], w0h[0][kf], acc00);
                acc01 = MFMA(a0[kf], w0h[1][kf], acc01);
                acc10 = MFMA(a1[kf], w0h[0][kf], acc10);
                acc11 = MFMA(a1[kf], w0h[1][kf], acc11);
            }
            #pragma unroll
            for (int r = 0; r < 4; ++r) {
                int r0 = quad * 4 + r, r1 = 16 + quad * 4 + r;
                part[w * 1184 + r0 * 37 + l16]      = acc00[r];
                part[w * 1184 + r0 * 37 + 16 + l16] = acc01[r];
                part[w * 1184 + r1 * 37 + l16]      = acc10[r];
                part[w * 1184 + r1 * 37 + 16 + l16] = acc11[r];
            }
            __syncthreads();
            if (tid < 256) {
                int b = tid >> 3, j = tid & 7;
                float g4[4];
                #pragma unroll
                for (int gg = 0; gg < 4; ++gg) {
                    float s = b0l[gg * 8 + j];
                    #pragma unroll
                    for (int w8 = 0; w8 < 8; ++w8)
                        s += part[w8 * 1184 + b * 37 + gg * 8 + j];
                    g4[gg] = s;
                }
                float c = c0l[tid];
                float cn = sigm(g4[1]) * c + sigm(g4[0]) * tanh_f(g4[2]);
                float hn = sigm(g4[3]) * tanh_f(cn);
                c0l[tid] = cn;
                llc_st16(h0w_ + cgp * 512 + (mh * 32 + b) * 8 + j, f2bf(hn));
            }
            __syncthreads();
        }

        // ---------- stage B: layer 1, step p-1 (A-operands already in flight) ----------
        if (p >= 1) {
            vm0();
            #pragma unroll
            for (int kf = 0; kf < 8; ++kf) { fence_frag(pb0[kf]); fence_frag(pb1[kf]); }
            f32x4 acc00 = {0.f,0.f,0.f,0.f}, acc01 = {0.f,0.f,0.f,0.f};
            f32x4 acc10 = {0.f,0.f,0.f,0.f}, acc11 = {0.f,0.f,0.f,0.f};
            #pragma unroll
            for (int kf = 0; kf < 8; ++kf) {
                acc00 = MFMA(pb0[kf], w1f[0][kf], acc00);
                acc01 = MFMA(pb0[kf], w1f[1][kf], acc01);
                acc10 = MFMA(pb1[kf], w1f[0][kf], acc10);
                acc11 = MFMA(pb1[kf], w1f[1][kf], acc11);
            }
            #pragma unroll
            for (int r = 0; r < 4; ++r) {
                int r0 = quad * 4 + r, r1 = 16 + quad * 4 + r;
                part[w * 1184 + r0 * 37 + l16]      = acc00[r];
                part[w * 1184 + r0 * 37 + 16 + l16] = acc01[r];
                part[w * 1184 + r1 * 37 + l16]      = acc10[r];
                part[w * 1184 + r1 * 37 + 16 + l16] = acc11[r];
            }
            __syncthreads();
            if (tid < 256) {
                int b = tid >> 3, j = tid & 7;
                float g4[4];
                #pragma unroll
                for (int gg = 0; gg < 4; ++gg) {
                    float s = b1l[gg * 8 + j];
                    #pragma unroll
                    for (int w8 = 0; w8 < 8; ++w8)
                        s += part[w8 * 1184 + b * 37 + gg * 8 + j];
                    g4[gg] = s;
                }
                float c = c1l[tid];
                float cn = sigm(g4[1]) * c + sigm(g4[0]) * tanh_f(g4[2]);
                float hn = sigm(g4[3]) * tanh_f(cn);
                c1l[tid] = cn;
                llc_st16(h1w_ + cgp * 512 + (mh * 32 + b) * 8 + j, f2bf(hn));
                if (p == S_) h1f[(mh * 32 + b) * 1024 + cgp * 8 + j] = hn;
            }
            __syncthreads();
        }

        // ---- barrier arrive (stores drained by the vm0+syncthreads above), then
        //      prefetch next x-part ----
        if (p < S_) {
            if (tid == 0)
                __hip_atomic_fetch_add(&bar[0], 1, __ATOMIC_RELAXED, __HIP_MEMORY_SCOPE_AGENT);
            if (p + 1 < S_) XPART(p + 1);
        }
    }
}

// ---------------- final FC: out[b,o] = h1 . Wfc[o] + bfc[o] ----------------
__global__ void fc_k(const float* __restrict__ h1f, const float* __restrict__ Wfc,
                     const float* __restrict__ bfc, float* __restrict__ out) {
    int idx = blockIdx.x * 256 + threadIdx.x;
    if (idx >= 64 * 1000) return;
    int o = idx % 1000;
    int b = idx / 1000;
    const float4* hr = (const float4*)(h1f + b * H_);
    const float4* wr = (const float4*)(Wfc + (size_t)o * H_);
    float s = 0.f;
    #pragma unroll 4
    for (int k = 0; k < 256; ++k) {
        float4 a = hr[k];
        float4 w = wr[k];
        s += a.x * w.x + a.y * w.y + a.z * w.z + a.w * w.w;
    }
    out[idx] = s + bfc[o];
}

extern "C" void kernel_launch(void* const* d_in, const int* in_sizes, int n_in,
                              void* d_out, int out_size, void* d_ws, size_t ws_size,
                              hipStream_t stream) {
    const float* x    = (const float*)d_in[0];
    const float* h0in = (const float*)d_in[1];
    const float* c0in = (const float*)d_in[2];
    const float* Wih0 = (const float*)d_in[3];
    const float* Whh0 = (const float*)d_in[4];
    const float* bih0 = (const float*)d_in[5];
    const float* bhh0 = (const float*)d_in[6];
    const float* Wih1 = (const float*)d_in[7];
    const float* Whh1 = (const float*)d_in[8];
    const float* bih1 = (const float*)d_in[9];
    const float* bhh1 = (const float*)d_in[10];
    const float* Wfc  = (const float*)d_in[11];
    const float* bfc  = (const float*)d_in[12];
    float* out = (float*)d_out;

    char* ws = (char*)d_ws;
    size_t off = 0;
    auto alloc = [&](size_t bytes) {
        void* p = ws + off;
        off += (bytes + 255) & ~(size_t)255;
        return p;
    };
    u16* W0c   = (u16*)alloc((size_t)4096 * 1536 * 2);
    u16* W1c   = (u16*)alloc((size_t)4096 * 2048 * 2);
    float* bias0 = (float*)alloc(4096 * 4);
    float* bias1 = (float*)alloc(4096 * 4);
    u16* h0A   = (u16*)alloc(B_ * H_ * 2);
    u16* h0B   = (u16*)alloc(B_ * H_ * 2);
    u16* h1A   = (u16*)alloc(B_ * H_ * 2);
    u16* h1B   = (u16*)alloc(B_ * H_ * 2);
    float* h1f = (float*)alloc(B_ * H_ * 4);
    int* bar   = (int*)alloc(4096);

    prep_w<<<786432 / 256, 256, 0, stream>>>(Wih0, Whh0, W0c, 512, 1536, 786432);
    prep_w<<<1048576 / 256, 256, 0, stream>>>(Wih1, Whh1, W1c, 1024, 2048, 1048576);
    prep_misc2<<<(8192 + 2 * B_ * H_ + 255) / 256, 256, 0, stream>>>(
        h0in, bih0, bhh0, bih1, bhh1, bias0, bias1, h0A, h0B, h1A, h1B, bar);

    void* args[] = {(void*)&x, (void*)&W0c, (void*)&W1c, (void*)&bias0, (void*)&bias1,
                    (void*)&c0in, (void*)&h0A, (void*)&h0B, (void*)&h1A, (void*)&h1B,
                    (void*)&h1f, (void*)&bar};
    hipLaunchCooperativeKernel((void*)lstm_persist, dim3(256), dim3(512), args, 0, stream);

    fc_k<<<(64000 + 255) / 256, 256, 0, stream>>>(h1f, Wfc, bfc, out);
}